// Round 6
// baseline (351.847 us; speedup 1.0000x reference)
//
#include <hip/hip_runtime.h>
#include <math.h>

#define LL 16384
#define HH 1024
#define PP 512
#define NP2 1024        // 2*PP (re/im interleaved: col 2p = re, 2p+1 = im)
#define CHUNK 64
#define NCHUNK 256

// 256x256 pipelined GEMM, r2 schedule (best measured: 52-54 us)
#define BM2 256
#define BN2 256
#define SUBK 32         // K-slice per ring slot
#define REG_U16 16384   // u16 per ring slot (A 256x32 = 8192 | B 256x32 = 8192)

typedef unsigned short u16;
typedef __attribute__((ext_vector_type(8))) short bf16x8;   // 8 bf16 = 4 VGPRs
typedef __attribute__((ext_vector_type(4))) float f32x4;

__device__ __forceinline__ u16 f2bf(float f) {
    unsigned u = __float_as_uint(f);
    unsigned r = 0x7fffu + ((u >> 16) & 1u);   // RNE
    return (u16)((u + r) >> 16);
}
__device__ __forceinline__ float bf2f(u16 x) {
    return __uint_as_float(((unsigned)x) << 16);
}

__device__ __forceinline__ void gload_lds16(const void* g, void* l) {
    __builtin_amdgcn_global_load_lds(
        (const __attribute__((address_space(1))) unsigned int*)g,
        (__attribute__((address_space(3))) unsigned int*)l, 16, 0, 0);
}

#define SB0 __builtin_amdgcn_sched_barrier(0)

// ---------------------------------------------------------------------------
// Merged prep kernel (bb | cp | u->bf16 | per-p constants), one launch.
// Also zeroes the gemm<0> arrival counter (block 20480, t==0) -- stream
// order guarantees it's reset before gemm<0> each iteration; this replaces
// the hipMemsetAsync that was the only new host-side call in the failed r5.
// ---------------------------------------------------------------------------
__global__ __launch_bounds__(256) void k_prep(
        const float* __restrict__ B, const float* __restrict__ C,
        const float* __restrict__ u, const float* __restrict__ lre,
        const float* __restrict__ lim, const float* __restrict__ logstep,
        u16* __restrict__ bb, u16* __restrict__ cp, u16* __restrict__ ub,
        float* __restrict__ lbre, float* __restrict__ lbim,
        float* __restrict__ ltre, float* __restrict__ ltim,
        unsigned* __restrict__ cnt) {
    const int bx = blockIdx.x;
    if (bx < 2048) {
        int t = bx * 256 + threadIdx.x;   // over P*H
        int p = t >> 10, h = t & 1023;
        float2 b = ((const float2*)B)[t];
        // inline gamma = (Lambda_bar - 1) / Lambda
        float dt = expf(logstep[p]);
        float ar = lre[p], ai = lim[p];
        float e = expf(ar * dt);
        float s, c;
        sincosf(ai * dt, &s, &c);
        float nr = e * c - 1.0f, ni = e * s;
        float den = ar * ar + ai * ai;
        float gr = (nr * ar + ni * ai) / den;
        float gi = (ni * ar - nr * ai) / den;
        bb[(size_t)(2 * p) * HH + h]     = f2bf(gr * b.x - gi * b.y);
        bb[(size_t)(2 * p + 1) * HH + h] = f2bf(gr * b.y + gi * b.x);
    } else if (bx < 4096) {
        int t = (bx - 2048) * 256 + threadIdx.x;   // over H*P
        int h = t >> 9, p = t & 511;
        float2 c = ((const float2*)C)[t];
        cp[(size_t)h * NP2 + 2 * p]     = f2bf(c.x);
        cp[(size_t)h * NP2 + 2 * p + 1] = f2bf(-c.y);
    } else if (bx < 20480) {
        size_t i = ((size_t)(bx - 4096) * 256 + threadIdx.x) * 4;
        float4 v = *(const float4*)&u[i];
        unsigned lo = (unsigned)f2bf(v.x) | ((unsigned)f2bf(v.y) << 16);
        unsigned hi = (unsigned)f2bf(v.z) | ((unsigned)f2bf(v.w) << 16);
        *(uint2*)&ub[i] = make_uint2(lo, hi);
    } else {
        if (bx == 20480 && threadIdx.x == 0) *cnt = 0u;
        int p = (bx - 20480) * 256 + threadIdx.x;
        if (p < PP) {
            float dt = expf(logstep[p]);
            float ar = lre[p], ai = lim[p];
            float e = expf(ar * dt);
            float s, c;
            sincosf(ai * dt, &s, &c);
            float Lr = e * c, Li = e * s;          // Lambda_bar
            lbre[p] = Lr; lbim[p] = Li;
            float tr = Lr, ti = Li;                // Lambda_bar^64 via 6 squarings
            for (int i6 = 0; i6 < 6; i6++) {
                float rr = tr * tr - ti * ti;
                float mm = 2.0f * tr * ti;
                tr = rr; ti = mm;
            }
            ltre[p] = tr; ltim[p] = ti;
        }
    }
}

// ---------------------------------------------------------------------------
// bf16 MFMA GEMM_BT: C[M x N] = A[M x K] * Bt[N x K]^T,  N = 1024 (4 tiles).
// 256x256 tile, 512 threads (8 waves, 2M x 4N, per-wave 128x64 output).
// r2 schedule (best measured; byte-identical main loop to r4): ring of 3
// K=32 slices; slice s+2 staged while slice s computes.  Per slice 2 phases
// of 16 MFMA, counted vmcnt(4) at slice boundary, lgkmcnt(0)+setprio around
// MFMA clusters, swizzled conflict-free LDS (r2 PMC: 0 conflicts).
// FUSE=0: C-tile bf16 -> 128KB LDS -> uint4 line stores + fused per-chunk
//         scan; last-block tail performs the cross-chunk carry scan
//         (replaces k_scan2) via device-scope atomic + threadfence.
// FUSE=1: out = 2*acc + bf2f(ubf)*Din[col], fp32 NONTEMPORAL direct store.
// ---------------------------------------------------------------------------
template<int FUSE>
__global__ __launch_bounds__(512, 2) void k_gemm2(
        const u16* __restrict__ A, const u16* __restrict__ Bt,
        void* __restrict__ outp, const int K,
        const u16* __restrict__ ubf, const float* __restrict__ Din,
        const float* __restrict__ lbre, const float* __restrict__ lbim,
        float* __restrict__ frO, float* __restrict__ fiO,
        const float* __restrict__ ltre, const float* __restrict__ ltim,
        float* __restrict__ crO, float* __restrict__ ciO,
        unsigned* __restrict__ cnt) {
    extern __shared__ u16 smem[];   // 128 KB alloc; ring uses first 96 KB
    const int b = blockIdx.x;
    const int xcd = b & 7, sidx = b >> 3;
    const int m0 = (xcd * 8 + (sidx >> 2)) * BM2;
    const int n0 = (sidx & 3) * BN2;
    const int t = threadIdx.x;
    const int lane = t & 63, wid = t >> 6;
    const int wm = (wid >> 2) * 128, wn = (wid & 3) * 64;
    const int frow = lane & 15, quad = (lane >> 4) & 3;

    f32x4 acc[8][4];
    #pragma unroll
    for (int i = 0; i < 8; i++)
        #pragma unroll
        for (int j = 0; j < 4; j++) acc[i][j] = (f32x4){0.f, 0.f, 0.f, 0.f};

    // staging: thread t -> LDS byte offset t*16 within region part (HW rule).
    // source 16B-seg = slot ^ ((row>>1)&3); +128-row gload preserves the key.
    const int sr = t >> 2, slot = t & 3;
    const int seg = slot ^ ((sr >> 1) & 3);
    const u16* gA = A + (size_t)(m0 + sr) * K + seg * 8;
    const u16* gB = Bt + (size_t)(n0 + sr) * K + seg * 8;
    const int ldst = sr * 32 + slot * 8;

    // fragment reads: physical slot quad^((frow>>1)&3) at row ...+frow holds
    // global seg quad.  Within a 16-lane group: 2 lanes/16B-quad -> free.
    const int aoff = (wm + frow) * 32 + ((quad ^ ((frow >> 1) & 3)) * 8);
    const int boff = (wn + frow) * 32 + ((quad ^ ((frow >> 1) & 3)) * 8);

    const int NT = K / SUBK;   // 32 for K=1024

    // prologue: stage slices 0 and 1
    {
        u16* d0 = smem + ldst;
        gload_lds16(gA,                     d0);
        gload_lds16(gA + (size_t)128 * K,   d0 + 4096);
        gload_lds16(gB,                     d0 + 8192);
        gload_lds16(gB + (size_t)128 * K,   d0 + 12288);
        u16* d1 = smem + REG_U16 + ldst;
        gload_lds16(gA + SUBK,                   d1);
        gload_lds16(gA + (size_t)128 * K + SUBK, d1 + 4096);
        gload_lds16(gB + SUBK,                   d1 + 8192);
        gload_lds16(gB + (size_t)128 * K + SUBK, d1 + 12288);
    }
    asm volatile("s_waitcnt vmcnt(4)" ::: "memory");   // slice 0 resident
    SB0;
    __builtin_amdgcn_s_barrier();
    SB0;

    int rc = 0;            // ring slot being computed
    int rs = 2;            // ring slot being staged (slice s+2)
    for (int s = 0; s < NT; ++s) {
        const u16* Ar = smem + rc * REG_U16;
        const u16* Br = Ar + 8192;
        const bool do_stage = (s + 2 < NT);
        const u16* gAs = gA + (size_t)(s + 2) * SUBK;
        const u16* gBs = gB + (size_t)(s + 2) * SUBK;
        u16* dS = smem + rs * REG_U16 + ldst;

        // ---- phase A: read av0..3 + bv0..3, stage A-halves, MFMA i=0..3 ----
        bf16x8 av0 = *(const bf16x8*)&Ar[aoff + 0 * 512];
        bf16x8 av1 = *(const bf16x8*)&Ar[aoff + 1 * 512];
        bf16x8 av2 = *(const bf16x8*)&Ar[aoff + 2 * 512];
        bf16x8 av3 = *(const bf16x8*)&Ar[aoff + 3 * 512];
        bf16x8 bv0 = *(const bf16x8*)&Br[boff + 0 * 512];
        bf16x8 bv1 = *(const bf16x8*)&Br[boff + 1 * 512];
        bf16x8 bv2 = *(const bf16x8*)&Br[boff + 2 * 512];
        bf16x8 bv3 = *(const bf16x8*)&Br[boff + 3 * 512];
        if (do_stage) {
            gload_lds16(gAs,                   dS);
            gload_lds16(gAs + (size_t)128 * K, dS + 4096);
        }
        SB0;
        __builtin_amdgcn_s_barrier();
        asm volatile("s_waitcnt lgkmcnt(0)" ::: "memory");
        SB0;
        __builtin_amdgcn_s_setprio(1);
        acc[0][0] = __builtin_amdgcn_mfma_f32_16x16x32_bf16(av0, bv0, acc[0][0], 0, 0, 0);
        acc[0][1] = __builtin_amdgcn_mfma_f32_16x16x32_bf16(av0, bv1, acc[0][1], 0, 0, 0);
        acc[0][2] = __builtin_amdgcn_mfma_f32_16x16x32_bf16(av0, bv2, acc[0][2], 0, 0, 0);
        acc[0][3] = __builtin_amdgcn_mfma_f32_16x16x32_bf16(av0, bv3, acc[0][3], 0, 0, 0);
        acc[1][0] = __builtin_amdgcn_mfma_f32_16x16x32_bf16(av1, bv0, acc[1][0], 0, 0, 0);
        acc[1][1] = __builtin_amdgcn_mfma_f32_16x16x32_bf16(av1, bv1, acc[1][1], 0, 0, 0);
        acc[1][2] = __builtin_amdgcn_mfma_f32_16x16x32_bf16(av1, bv2, acc[1][2], 0, 0, 0);
        acc[1][3] = __builtin_amdgcn_mfma_f32_16x16x32_bf16(av1, bv3, acc[1][3], 0, 0, 0);
        acc[2][0] = __builtin_amdgcn_mfma_f32_16x16x32_bf16(av2, bv0, acc[2][0], 0, 0, 0);
        acc[2][1] = __builtin_amdgcn_mfma_f32_16x16x32_bf16(av2, bv1, acc[2][1], 0, 0, 0);
        acc[2][2] = __builtin_amdgcn_mfma_f32_16x16x32_bf16(av2, bv2, acc[2][2], 0, 0, 0);
        acc[2][3] = __builtin_amdgcn_mfma_f32_16x16x32_bf16(av2, bv3, acc[2][3], 0, 0, 0);
        acc[3][0] = __builtin_amdgcn_mfma_f32_16x16x32_bf16(av3, bv0, acc[3][0], 0, 0, 0);
        acc[3][1] = __builtin_amdgcn_mfma_f32_16x16x32_bf16(av3, bv1, acc[3][1], 0, 0, 0);
        acc[3][2] = __builtin_amdgcn_mfma_f32_16x16x32_bf16(av3, bv2, acc[3][2], 0, 0, 0);
        acc[3][3] = __builtin_amdgcn_mfma_f32_16x16x32_bf16(av3, bv3, acc[3][3], 0, 0, 0);
        __builtin_amdgcn_s_setprio(0);
        SB0;
        __builtin_amdgcn_s_barrier();
        SB0;

        // ---- phase B: read av4..7, stage B-halves, MFMA i=4..7 ----
        bf16x8 av4 = *(const bf16x8*)&Ar[aoff + 4 * 512];
        bf16x8 av5 = *(const bf16x8*)&Ar[aoff + 5 * 512];
        bf16x8 av6 = *(const bf16x8*)&Ar[aoff + 6 * 512];
        bf16x8 av7 = *(const bf16x8*)&Ar[aoff + 7 * 512];
        if (do_stage) {
            gload_lds16(gBs,                   dS + 8192);
            gload_lds16(gBs + (size_t)128 * K, dS + 12288);
        }
        SB0;
        __builtin_amdgcn_s_barrier();
        asm volatile("s_waitcnt lgkmcnt(0)" ::: "memory");
        SB0;
        __builtin_amdgcn_s_setprio(1);
        acc[4][0] = __builtin_amdgcn_mfma_f32_16x16x32_bf16(av4, bv0, acc[4][0], 0, 0, 0);
        acc[4][1] = __builtin_amdgcn_mfma_f32_16x16x32_bf16(av4, bv1, acc[4][1], 0, 0, 0);
        acc[4][2] = __builtin_amdgcn_mfma_f32_16x16x32_bf16(av4, bv2, acc[4][2], 0, 0, 0);
        acc[4][3] = __builtin_amdgcn_mfma_f32_16x16x32_bf16(av4, bv3, acc[4][3], 0, 0, 0);
        acc[5][0] = __builtin_amdgcn_mfma_f32_16x16x32_bf16(av5, bv0, acc[5][0], 0, 0, 0);
        acc[5][1] = __builtin_amdgcn_mfma_f32_16x16x32_bf16(av5, bv1, acc[5][1], 0, 0, 0);
        acc[5][2] = __builtin_amdgcn_mfma_f32_16x16x32_bf16(av5, bv2, acc[5][2], 0, 0, 0);
        acc[5][3] = __builtin_amdgcn_mfma_f32_16x16x32_bf16(av5, bv3, acc[5][3], 0, 0, 0);
        acc[6][0] = __builtin_amdgcn_mfma_f32_16x16x32_bf16(av6, bv0, acc[6][0], 0, 0, 0);
        acc[6][1] = __builtin_amdgcn_mfma_f32_16x16x32_bf16(av6, bv1, acc[6][1], 0, 0, 0);
        acc[6][2] = __builtin_amdgcn_mfma_f32_16x16x32_bf16(av6, bv2, acc[6][2], 0, 0, 0);
        acc[6][3] = __builtin_amdgcn_mfma_f32_16x16x32_bf16(av6, bv3, acc[6][3], 0, 0, 0);
        acc[7][0] = __builtin_amdgcn_mfma_f32_16x16x32_bf16(av7, bv0, acc[7][0], 0, 0, 0);
        acc[7][1] = __builtin_amdgcn_mfma_f32_16x16x32_bf16(av7, bv1, acc[7][1], 0, 0, 0);
        acc[7][2] = __builtin_amdgcn_mfma_f32_16x16x32_bf16(av7, bv2, acc[7][2], 0, 0, 0);
        acc[7][3] = __builtin_amdgcn_mfma_f32_16x16x32_bf16(av7, bv3, acc[7][3], 0, 0, 0);
        __builtin_amdgcn_s_setprio(0);
        // counted boundary wait: slice s+1's 4 loads (staged during s-1) must
        // be resident; the 4 newest (slice s+2, staged this slice) may fly.
        if (s < NT - 2)       asm volatile("s_waitcnt vmcnt(4)" ::: "memory");
        else if (s == NT - 2) asm volatile("s_waitcnt vmcnt(0)" ::: "memory");
        SB0;
        __builtin_amdgcn_s_barrier();
        SB0;

        rc = (rc == 2) ? 0 : rc + 1;
        rs = (rs == 2) ? 0 : rs + 1;
    }

    if (FUSE) {
        float* Cout = (float*)outp;
        #pragma unroll
        for (int i = 0; i < 8; i++) {
            const int row = m0 + wm + i * 16 + quad * 4;   // + r
            #pragma unroll
            for (int j = 0; j < 4; j++) {
                const int col = n0 + wn + j * 16 + frow;
                const float dv = Din[col];
                f32x4 v = acc[i][j];
                #pragma unroll
                for (int r = 0; r < 4; r++) {
                    const size_t o = (size_t)(row + r) * 1024 + col;
                    __builtin_nontemporal_store(
                        2.0f * v[r] + bf2f(ubf[o]) * dv, &Cout[o]);
                }
            }
        }
    } else {
        // Full C-tile (256x256 bf16 = 128 KB) into LDS, then coalesced uint4
        // stores + fused per-chunk scan (4 chunks x 128 complex p, 512 thr).
        u16* Cb = (u16*)outp;
        unsigned* sm32 = (unsigned*)smem;
        #pragma unroll
        for (int i = 0; i < 8; i++)
            #pragma unroll
            for (int j = 0; j < 4; j++) {
                f32x4 v = acc[i][j];
                #pragma unroll
                for (int r = 0; r < 4; r++)
                    smem[(wm + i * 16 + quad * 4 + r) * 256 + wn + j * 16 + frow]
                        = f2bf(v[r]);
            }
        __syncthreads();
        #pragma unroll
        for (int k = 0; k < 16; k++) {
            const int l = t + k * 512;
            const int row = l >> 5, c16 = (l & 31) * 8;
            *(uint4*)&Cb[(size_t)(m0 + row) * 1024 + n0 + c16] =
                ((const uint4*)smem)[l];
        }
        const int ch = t >> 7, q = t & 127;
        const int sp = (n0 >> 1) + q;
        const float sar = lbre[sp], sai = lbim[sp];
        float xr = 0.f, xi = 0.f;
        #pragma unroll 8
        for (int r = 0; r < 64; r++) {
            unsigned v = sm32[(ch * 64 + r) * 128 + q];
            float br = bf2f((u16)(v & 0xffff));
            float bi = bf2f((u16)(v >> 16));
            float nr = sar * xr - sai * xi + br;
            float ni = sar * xi + sai * xr + bi;
            xr = nr; xi = ni;
        }
        frO[((m0 >> 6) + ch) * PP + sp] = xr;
        fiO[((m0 >> 6) + ch) * PP + sp] = xi;

        // ---- fused cross-chunk carry scan (replaces k_scan2) ----
        // Release our fr/fi stores, count arrivals (device-scope), last
        // block's 512 threads (= 512 p) run the sequential 256-chunk scan.
        __threadfence();
        __shared__ unsigned is_last;
        if (t == 0)
            is_last = (atomicAdd(cnt, 1u) == gridDim.x - 1) ? 1u : 0u;
        __syncthreads();
        if (is_last) {
            __threadfence();   // acquire all blocks' fr/fi
            const int p = t;
            const float lr = ltre[p], li = ltim[p];
            float cxr = 0.f, cxi = 0.f;
            for (int c = 0; c < NCHUNK; c += 4) {
                float f0r = frO[(c + 0) * PP + p], f0i = fiO[(c + 0) * PP + p];
                float f1r = frO[(c + 1) * PP + p], f1i = fiO[(c + 1) * PP + p];
                float f2r = frO[(c + 2) * PP + p], f2i = fiO[(c + 2) * PP + p];
                float f3r = frO[(c + 3) * PP + p], f3i = fiO[(c + 3) * PP + p];
                float nr, ni;
                crO[(c + 0) * PP + p] = cxr; ciO[(c + 0) * PP + p] = cxi;
                nr = lr * cxr - li * cxi + f0r; ni = lr * cxi + li * cxr + f0i;
                cxr = nr; cxi = ni;
                crO[(c + 1) * PP + p] = cxr; ciO[(c + 1) * PP + p] = cxi;
                nr = lr * cxr - li * cxi + f1r; ni = lr * cxi + li * cxr + f1i;
                cxr = nr; cxi = ni;
                crO[(c + 2) * PP + p] = cxr; ciO[(c + 2) * PP + p] = cxi;
                nr = lr * cxr - li * cxi + f2r; ni = lr * cxi + li * cxr + f2i;
                cxr = nr; cxi = ni;
                crO[(c + 3) * PP + p] = cxr; ciO[(c + 3) * PP + p] = cxi;
                nr = lr * cxr - li * cxi + f3r; ni = lr * cxi + li * cxr + f3i;
                cxr = nr; cxi = ni;
            }
        }
    }
}

// ---------------------------------------------------------------------------
// Scan pass 3: replay with carry; overwrite Bu with xs in-place.
// Interleaved layout: one u32 = (re,im) bf16 pair per p -> coalesced.
// 8x-batched loads so HBM/L3 latency overlaps the serial complex chain.
// ---------------------------------------------------------------------------
__global__ void k_scan3(unsigned* __restrict__ bu,
                        const float* __restrict__ lbre, const float* __restrict__ lbim,
                        const float* __restrict__ cr, const float* __restrict__ ci) {
    int p = blockIdx.x * 256 + threadIdx.x;
    int c = blockIdx.y;
    float ar = lbre[p], ai = lbim[p];
    float xr = cr[c * PP + p], xi = ci[c * PP + p];
    unsigned* b = bu + (size_t)c * CHUNK * PP + p;
    for (int j = 0; j < CHUNK; j += 8) {
        unsigned vv[8];
        #pragma unroll
        for (int q = 0; q < 8; q++) vv[q] = b[q * PP];
        unsigned w[8];
        #pragma unroll
        for (int q = 0; q < 8; q++) {
            float br = bf2f((u16)(vv[q] & 0xffff));
            float bi = bf2f((u16)(vv[q] >> 16));
            float nr = ar * xr - ai * xi + br;
            float ni = ar * xi + ai * xr + bi;
            xr = nr; xi = ni;
            w[q] = (unsigned)f2bf(xr) | ((unsigned)f2bf(xi) << 16);
        }
        #pragma unroll
        for (int q = 0; q < 8; q++) b[q * PP] = w[q];
        b += 8 * PP;
    }
}

extern "C" void kernel_launch(void* const* d_in, const int* in_sizes, int n_in,
                              void* d_out, int out_size, void* d_ws, size_t ws_size,
                              hipStream_t stream) {
    const float* u       = (const float*)d_in[0];   // (L,H)
    const float* lre     = (const float*)d_in[1];   // (P,)
    const float* lim     = (const float*)d_in[2];   // (P,)
    const float* B       = (const float*)d_in[3];   // (P,H,2)
    const float* C       = (const float*)d_in[4];   // (H,P,2)
    const float* D       = (const float*)d_in[5];   // (H,)
    const float* logstep = (const float*)d_in[6];   // (P,)
    float* out = (float*)d_out;

    float* w = (float*)d_ws;
    float* lbre = w + 1024;
    float* lbim = w + 1536;
    float* ltre = w + 2048;
    float* ltim = w + 2560;
    unsigned* cnt = (unsigned*)(w + 3072);
    float* fr   = w + 4096;                       // NCHUNK*PP each
    float* fi   = fr + NCHUNK * PP;
    float* cr   = fi + NCHUNK * PP;
    float* ci   = cr + NCHUNK * PP;
    u16*   bub  = (u16*)(w + (1 << 20));          // L*2P bf16 = 32 MB (Bu -> xs in-place)
    u16*   ub   = bub + (size_t)LL * NP2;         // L*H bf16 = 32 MB
    u16*   bb   = ub + (size_t)LL * HH;           // 2P*H bf16 = 2 MB
    u16*   cp   = bb + (size_t)NP2 * HH;          // H*2P bf16 = 2 MB

    static int attr_done = 0;
    if (!attr_done) {
        hipFuncSetAttribute(reinterpret_cast<const void*>(k_gemm2<0>),
                            hipFuncAttributeMaxDynamicSharedMemorySize, 131072);
        hipFuncSetAttribute(reinterpret_cast<const void*>(k_gemm2<1>),
                            hipFuncAttributeMaxDynamicSharedMemorySize, 131072);
        attr_done = 1;
    }

    k_prep<<<20482, 256, 0, stream>>>(B, C, u, lre, lim, logstep,
                                      bb, cp, ub, lbre, lbim, ltre, ltim, cnt);
    k_gemm2<0><<<(NP2 / BN2) * (LL / BM2), 512, 131072, stream>>>(
        ub, bb, bub, HH, nullptr, nullptr, lbre, lbim, fr, fi,
        ltre, ltim, cr, ci, cnt);
    k_scan3<<<dim3(PP / 256, NCHUNK), 256, 0, stream>>>(
        (unsigned*)bub, lbre, lbim, cr, ci);
    k_gemm2<1><<<(HH / BN2) * (LL / BM2), 512, 131072, stream>>>(
        bub, cp, out, NP2, ub, D, nullptr, nullptr, nullptr, nullptr,
        nullptr, nullptr, nullptr, nullptr, nullptr);
}

// Round 7
// 228.302 us; speedup vs baseline: 1.5412x; 1.5412x over previous
//
#include <hip/hip_runtime.h>
#include <math.h>

#define LL 16384
#define HH 1024
#define PP 512
#define NP2 1024        // 2*PP (re/im interleaved: col 2p = re, 2p+1 = im)
#define CHUNK 64
#define NCHUNK 256

// 256x256 pipelined GEMM, r2 schedule (best measured: 52-54 us)
#define BM2 256
#define BN2 256
#define SUBK 32         // K-slice per ring slot
#define REG_U16 16384   // u16 per ring slot (A 256x32 = 8192 | B 256x32 = 8192)

typedef unsigned short u16;
typedef __attribute__((ext_vector_type(8))) short bf16x8;   // 8 bf16 = 4 VGPRs
typedef __attribute__((ext_vector_type(4))) float f32x4;

__device__ __forceinline__ u16 f2bf(float f) {
    unsigned u = __float_as_uint(f);
    unsigned r = 0x7fffu + ((u >> 16) & 1u);   // RNE
    return (u16)((u + r) >> 16);
}
__device__ __forceinline__ float bf2f(u16 x) {
    return __uint_as_float(((unsigned)x) << 16);
}

__device__ __forceinline__ void gload_lds16(const void* g, void* l) {
    __builtin_amdgcn_global_load_lds(
        (const __attribute__((address_space(1))) unsigned int*)g,
        (__attribute__((address_space(3))) unsigned int*)l, 16, 0, 0);
}

#define SB0 __builtin_amdgcn_sched_barrier(0)

// ---------------------------------------------------------------------------
// Merged prep kernel (bb | cp | u->bf16 | per-p constants), one launch.
// ---------------------------------------------------------------------------
__global__ __launch_bounds__(256) void k_prep(
        const float* __restrict__ B, const float* __restrict__ C,
        const float* __restrict__ u, const float* __restrict__ lre,
        const float* __restrict__ lim, const float* __restrict__ logstep,
        u16* __restrict__ bb, u16* __restrict__ cp, u16* __restrict__ ub,
        float* __restrict__ lbre, float* __restrict__ lbim,
        float* __restrict__ ltre, float* __restrict__ ltim) {
    const int bx = blockIdx.x;
    if (bx < 2048) {
        int t = bx * 256 + threadIdx.x;   // over P*H
        int p = t >> 10, h = t & 1023;
        float2 b = ((const float2*)B)[t];
        // inline gamma = (Lambda_bar - 1) / Lambda
        float dt = expf(logstep[p]);
        float ar = lre[p], ai = lim[p];
        float e = expf(ar * dt);
        float s, c;
        sincosf(ai * dt, &s, &c);
        float nr = e * c - 1.0f, ni = e * s;
        float den = ar * ar + ai * ai;
        float gr = (nr * ar + ni * ai) / den;
        float gi = (ni * ar - nr * ai) / den;
        bb[(size_t)(2 * p) * HH + h]     = f2bf(gr * b.x - gi * b.y);
        bb[(size_t)(2 * p + 1) * HH + h] = f2bf(gr * b.y + gi * b.x);
    } else if (bx < 4096) {
        int t = (bx - 2048) * 256 + threadIdx.x;   // over H*P
        int h = t >> 9, p = t & 511;
        float2 c = ((const float2*)C)[t];
        cp[(size_t)h * NP2 + 2 * p]     = f2bf(c.x);
        cp[(size_t)h * NP2 + 2 * p + 1] = f2bf(-c.y);
    } else if (bx < 20480) {
        size_t i = ((size_t)(bx - 4096) * 256 + threadIdx.x) * 4;
        float4 v = *(const float4*)&u[i];
        unsigned lo = (unsigned)f2bf(v.x) | ((unsigned)f2bf(v.y) << 16);
        unsigned hi = (unsigned)f2bf(v.z) | ((unsigned)f2bf(v.w) << 16);
        *(uint2*)&ub[i] = make_uint2(lo, hi);
    } else {
        int p = (bx - 20480) * 256 + threadIdx.x;
        if (p < PP) {
            float dt = expf(logstep[p]);
            float ar = lre[p], ai = lim[p];
            float e = expf(ar * dt);
            float s, c;
            sincosf(ai * dt, &s, &c);
            float Lr = e * c, Li = e * s;          // Lambda_bar
            lbre[p] = Lr; lbim[p] = Li;
            float tr = Lr, ti = Li;                // Lambda_bar^64 via 6 squarings
            for (int i6 = 0; i6 < 6; i6++) {
                float rr = tr * tr - ti * ti;
                float mm = 2.0f * tr * ti;
                tr = rr; ti = mm;
            }
            ltre[p] = tr; ltim[p] = ti;
        }
    }
}

// ---------------------------------------------------------------------------
// bf16 MFMA GEMM_BT: C[M x N] = A[M x K] * Bt[N x K]^T,  N = 1024 (4 tiles).
// 256x256 tile, 512 threads (8 waves, 2M x 4N, per-wave 128x64 output).
// r2/r4 schedule (best measured; main loop byte-identical): ring of 3
// K=32 slices; slice s+2 staged while slice s computes.  Per slice 2 phases
// of 16 MFMA, counted vmcnt(4) at slice boundary, lgkmcnt(0)+setprio around
// MFMA clusters, swizzled conflict-free LDS (r2 PMC: 0 conflicts).
// NOTE (r6 ledger): cross-block fused carry-scan via __threadfence/atomic
// cost +125 us (L2 invalidate + serial single-CU tail) -- never refuse a
// 1 us dispatch by paying device-fence prices.  Keep scan2 separate.
// FUSE=0: C-tile bf16 -> full 128KB LDS -> uint4 line stores + fused
//         per-chunk scan with all 512 threads (4 chunks x 128 p).
// FUSE=1: out = 2*acc + bf2f(ubf)*Din[col], fp32 NONTEMPORAL direct store
//         (out is write-once; keeps L2 for ubf reads).
// ---------------------------------------------------------------------------
template<int FUSE>
__global__ __launch_bounds__(512, 2) void k_gemm2(
        const u16* __restrict__ A, const u16* __restrict__ Bt,
        void* __restrict__ outp, const int K,
        const u16* __restrict__ ubf, const float* __restrict__ Din,
        const float* __restrict__ lbre, const float* __restrict__ lbim,
        float* __restrict__ frO, float* __restrict__ fiO) {
    extern __shared__ u16 smem[];   // 128 KB alloc; ring uses first 96 KB
    const int b = blockIdx.x;
    const int xcd = b & 7, sidx = b >> 3;
    const int m0 = (xcd * 8 + (sidx >> 2)) * BM2;
    const int n0 = (sidx & 3) * BN2;
    const int t = threadIdx.x;
    const int lane = t & 63, wid = t >> 6;
    const int wm = (wid >> 2) * 128, wn = (wid & 3) * 64;
    const int frow = lane & 15, quad = (lane >> 4) & 3;

    f32x4 acc[8][4];
    #pragma unroll
    for (int i = 0; i < 8; i++)
        #pragma unroll
        for (int j = 0; j < 4; j++) acc[i][j] = (f32x4){0.f, 0.f, 0.f, 0.f};

    // staging: thread t -> LDS byte offset t*16 within region part (HW rule).
    // source 16B-seg = slot ^ ((row>>1)&3); +128-row gload preserves the key.
    const int sr = t >> 2, slot = t & 3;
    const int seg = slot ^ ((sr >> 1) & 3);
    const u16* gA = A + (size_t)(m0 + sr) * K + seg * 8;
    const u16* gB = Bt + (size_t)(n0 + sr) * K + seg * 8;
    const int ldst = sr * 32 + slot * 8;

    // fragment reads: physical slot quad^((frow>>1)&3) at row ...+frow holds
    // global seg quad.  Within a 16-lane group: 2 lanes/16B-quad -> free.
    const int aoff = (wm + frow) * 32 + ((quad ^ ((frow >> 1) & 3)) * 8);
    const int boff = (wn + frow) * 32 + ((quad ^ ((frow >> 1) & 3)) * 8);

    const int NT = K / SUBK;   // 32 for K=1024

    // prologue: stage slices 0 and 1
    {
        u16* d0 = smem + ldst;
        gload_lds16(gA,                     d0);
        gload_lds16(gA + (size_t)128 * K,   d0 + 4096);
        gload_lds16(gB,                     d0 + 8192);
        gload_lds16(gB + (size_t)128 * K,   d0 + 12288);
        u16* d1 = smem + REG_U16 + ldst;
        gload_lds16(gA + SUBK,                   d1);
        gload_lds16(gA + (size_t)128 * K + SUBK, d1 + 4096);
        gload_lds16(gB + SUBK,                   d1 + 8192);
        gload_lds16(gB + (size_t)128 * K + SUBK, d1 + 12288);
    }
    asm volatile("s_waitcnt vmcnt(4)" ::: "memory");   // slice 0 resident
    SB0;
    __builtin_amdgcn_s_barrier();
    SB0;

    int rc = 0;            // ring slot being computed
    int rs = 2;            // ring slot being staged (slice s+2)
    for (int s = 0; s < NT; ++s) {
        const u16* Ar = smem + rc * REG_U16;
        const u16* Br = Ar + 8192;
        const bool do_stage = (s + 2 < NT);
        const u16* gAs = gA + (size_t)(s + 2) * SUBK;
        const u16* gBs = gB + (size_t)(s + 2) * SUBK;
        u16* dS = smem + rs * REG_U16 + ldst;

        // ---- phase A: read av0..3 + bv0..3, stage A-halves, MFMA i=0..3 ----
        bf16x8 av0 = *(const bf16x8*)&Ar[aoff + 0 * 512];
        bf16x8 av1 = *(const bf16x8*)&Ar[aoff + 1 * 512];
        bf16x8 av2 = *(const bf16x8*)&Ar[aoff + 2 * 512];
        bf16x8 av3 = *(const bf16x8*)&Ar[aoff + 3 * 512];
        bf16x8 bv0 = *(const bf16x8*)&Br[boff + 0 * 512];
        bf16x8 bv1 = *(const bf16x8*)&Br[boff + 1 * 512];
        bf16x8 bv2 = *(const bf16x8*)&Br[boff + 2 * 512];
        bf16x8 bv3 = *(const bf16x8*)&Br[boff + 3 * 512];
        if (do_stage) {
            gload_lds16(gAs,                   dS);
            gload_lds16(gAs + (size_t)128 * K, dS + 4096);
        }
        SB0;
        __builtin_amdgcn_s_barrier();
        asm volatile("s_waitcnt lgkmcnt(0)" ::: "memory");
        SB0;
        __builtin_amdgcn_s_setprio(1);
        acc[0][0] = __builtin_amdgcn_mfma_f32_16x16x32_bf16(av0, bv0, acc[0][0], 0, 0, 0);
        acc[0][1] = __builtin_amdgcn_mfma_f32_16x16x32_bf16(av0, bv1, acc[0][1], 0, 0, 0);
        acc[0][2] = __builtin_amdgcn_mfma_f32_16x16x32_bf16(av0, bv2, acc[0][2], 0, 0, 0);
        acc[0][3] = __builtin_amdgcn_mfma_f32_16x16x32_bf16(av0, bv3, acc[0][3], 0, 0, 0);
        acc[1][0] = __builtin_amdgcn_mfma_f32_16x16x32_bf16(av1, bv0, acc[1][0], 0, 0, 0);
        acc[1][1] = __builtin_amdgcn_mfma_f32_16x16x32_bf16(av1, bv1, acc[1][1], 0, 0, 0);
        acc[1][2] = __builtin_amdgcn_mfma_f32_16x16x32_bf16(av1, bv2, acc[1][2], 0, 0, 0);
        acc[1][3] = __builtin_amdgcn_mfma_f32_16x16x32_bf16(av1, bv3, acc[1][3], 0, 0, 0);
        acc[2][0] = __builtin_amdgcn_mfma_f32_16x16x32_bf16(av2, bv0, acc[2][0], 0, 0, 0);
        acc[2][1] = __builtin_amdgcn_mfma_f32_16x16x32_bf16(av2, bv1, acc[2][1], 0, 0, 0);
        acc[2][2] = __builtin_amdgcn_mfma_f32_16x16x32_bf16(av2, bv2, acc[2][2], 0, 0, 0);
        acc[2][3] = __builtin_amdgcn_mfma_f32_16x16x32_bf16(av2, bv3, acc[2][3], 0, 0, 0);
        acc[3][0] = __builtin_amdgcn_mfma_f32_16x16x32_bf16(av3, bv0, acc[3][0], 0, 0, 0);
        acc[3][1] = __builtin_amdgcn_mfma_f32_16x16x32_bf16(av3, bv1, acc[3][1], 0, 0, 0);
        acc[3][2] = __builtin_amdgcn_mfma_f32_16x16x32_bf16(av3, bv2, acc[3][2], 0, 0, 0);
        acc[3][3] = __builtin_amdgcn_mfma_f32_16x16x32_bf16(av3, bv3, acc[3][3], 0, 0, 0);
        __builtin_amdgcn_s_setprio(0);
        SB0;
        __builtin_amdgcn_s_barrier();
        SB0;

        // ---- phase B: read av4..7, stage B-halves, MFMA i=4..7 ----
        bf16x8 av4 = *(const bf16x8*)&Ar[aoff + 4 * 512];
        bf16x8 av5 = *(const bf16x8*)&Ar[aoff + 5 * 512];
        bf16x8 av6 = *(const bf16x8*)&Ar[aoff + 6 * 512];
        bf16x8 av7 = *(const bf16x8*)&Ar[aoff + 7 * 512];
        if (do_stage) {
            gload_lds16(gBs,                   dS + 8192);
            gload_lds16(gBs + (size_t)128 * K, dS + 12288);
        }
        SB0;
        __builtin_amdgcn_s_barrier();
        asm volatile("s_waitcnt lgkmcnt(0)" ::: "memory");
        SB0;
        __builtin_amdgcn_s_setprio(1);
        acc[4][0] = __builtin_amdgcn_mfma_f32_16x16x32_bf16(av4, bv0, acc[4][0], 0, 0, 0);
        acc[4][1] = __builtin_amdgcn_mfma_f32_16x16x32_bf16(av4, bv1, acc[4][1], 0, 0, 0);
        acc[4][2] = __builtin_amdgcn_mfma_f32_16x16x32_bf16(av4, bv2, acc[4][2], 0, 0, 0);
        acc[4][3] = __builtin_amdgcn_mfma_f32_16x16x32_bf16(av4, bv3, acc[4][3], 0, 0, 0);
        acc[5][0] = __builtin_amdgcn_mfma_f32_16x16x32_bf16(av5, bv0, acc[5][0], 0, 0, 0);
        acc[5][1] = __builtin_amdgcn_mfma_f32_16x16x32_bf16(av5, bv1, acc[5][1], 0, 0, 0);
        acc[5][2] = __builtin_amdgcn_mfma_f32_16x16x32_bf16(av5, bv2, acc[5][2], 0, 0, 0);
        acc[5][3] = __builtin_amdgcn_mfma_f32_16x16x32_bf16(av5, bv3, acc[5][3], 0, 0, 0);
        acc[6][0] = __builtin_amdgcn_mfma_f32_16x16x32_bf16(av6, bv0, acc[6][0], 0, 0, 0);
        acc[6][1] = __builtin_amdgcn_mfma_f32_16x16x32_bf16(av6, bv1, acc[6][1], 0, 0, 0);
        acc[6][2] = __builtin_amdgcn_mfma_f32_16x16x32_bf16(av6, bv2, acc[6][2], 0, 0, 0);
        acc[6][3] = __builtin_amdgcn_mfma_f32_16x16x32_bf16(av6, bv3, acc[6][3], 0, 0, 0);
        acc[7][0] = __builtin_amdgcn_mfma_f32_16x16x32_bf16(av7, bv0, acc[7][0], 0, 0, 0);
        acc[7][1] = __builtin_amdgcn_mfma_f32_16x16x32_bf16(av7, bv1, acc[7][1], 0, 0, 0);
        acc[7][2] = __builtin_amdgcn_mfma_f32_16x16x32_bf16(av7, bv2, acc[7][2], 0, 0, 0);
        acc[7][3] = __builtin_amdgcn_mfma_f32_16x16x32_bf16(av7, bv3, acc[7][3], 0, 0, 0);
        __builtin_amdgcn_s_setprio(0);
        // counted boundary wait: slice s+1's 4 loads (staged during s-1) must
        // be resident; the 4 newest (slice s+2, staged this slice) may fly.
        if (s < NT - 2)       asm volatile("s_waitcnt vmcnt(4)" ::: "memory");
        else if (s == NT - 2) asm volatile("s_waitcnt vmcnt(0)" ::: "memory");
        SB0;
        __builtin_amdgcn_s_barrier();
        SB0;

        rc = (rc == 2) ? 0 : rc + 1;
        rs = (rs == 2) ? 0 : rs + 1;
    }

    if (FUSE) {
        float* Cout = (float*)outp;
        #pragma unroll
        for (int i = 0; i < 8; i++) {
            const int row = m0 + wm + i * 16 + quad * 4;   // + r
            #pragma unroll
            for (int j = 0; j < 4; j++) {
                const int col = n0 + wn + j * 16 + frow;
                const float dv = Din[col];
                f32x4 v = acc[i][j];
                #pragma unroll
                for (int r = 0; r < 4; r++) {
                    const size_t o = (size_t)(row + r) * 1024 + col;
                    __builtin_nontemporal_store(
                        2.0f * v[r] + bf2f(ubf[o]) * dv, &Cout[o]);
                }
            }
        }
    } else {
        // Full C-tile (256x256 bf16 = 128 KB) into LDS, then coalesced uint4
        // stores + fused per-chunk scan (4 chunks x 128 complex p, 512 thr).
        u16* Cb = (u16*)outp;
        unsigned* sm32 = (unsigned*)smem;
        #pragma unroll
        for (int i = 0; i < 8; i++)
            #pragma unroll
            for (int j = 0; j < 4; j++) {
                f32x4 v = acc[i][j];
                #pragma unroll
                for (int r = 0; r < 4; r++)
                    smem[(wm + i * 16 + quad * 4 + r) * 256 + wn + j * 16 + frow]
                        = f2bf(v[r]);
            }
        __syncthreads();
        #pragma unroll
        for (int k = 0; k < 16; k++) {
            const int l = t + k * 512;
            const int row = l >> 5, c16 = (l & 31) * 8;
            *(uint4*)&Cb[(size_t)(m0 + row) * 1024 + n0 + c16] =
                ((const uint4*)smem)[l];
        }
        const int ch = t >> 7, q = t & 127;
        const int sp = (n0 >> 1) + q;
        const float sar = lbre[sp], sai = lbim[sp];
        float xr = 0.f, xi = 0.f;
        #pragma unroll 8
        for (int r = 0; r < 64; r++) {
            unsigned v = sm32[(ch * 64 + r) * 128 + q];
            float br = bf2f((u16)(v & 0xffff));
            float bi = bf2f((u16)(v >> 16));
            float nr = sar * xr - sai * xi + br;
            float ni = sar * xi + sai * xr + bi;
            xr = nr; xi = ni;
        }
        frO[((m0 >> 6) + ch) * PP + sp] = xr;
        fiO[((m0 >> 6) + ch) * PP + sp] = xi;
    }
}

// ---------------------------------------------------------------------------
// Scan pass 2 (parallel): one block per p, one thread per chunk.
// Hillis-Steele inclusive scan of (A = Lambda^T, b = f) pairs in LDS.
// ---------------------------------------------------------------------------
__global__ __launch_bounds__(256) void k_scan2(
        const float* __restrict__ fr, const float* __restrict__ fi,
        const float* __restrict__ ltre, const float* __restrict__ ltim,
        float* __restrict__ cr, float* __restrict__ ci) {
    __shared__ float Ar[NCHUNK], Ai[NCHUNK], br[NCHUNK], bi[NCHUNK];
    const int p = blockIdx.x;
    const int c = threadIdx.x;
    const float lr = ltre[p], li = ltim[p];
    Ar[c] = lr; Ai[c] = li;
    br[c] = fr[c * PP + p];
    bi[c] = fi[c * PP + p];
    __syncthreads();
    #pragma unroll
    for (int d = 1; d < NCHUNK; d <<= 1) {
        float pAr = 0.f, pAi = 0.f, pbr = 0.f, pbi = 0.f;
        const bool has = (c >= d);
        if (has) { pAr = Ar[c-d]; pAi = Ai[c-d]; pbr = br[c-d]; pbi = bi[c-d]; }
        float cAr = Ar[c], cAi = Ai[c], cbr = br[c], cbi = bi[c];
        __syncthreads();
        if (has) {
            Ar[c] = cAr * pAr - cAi * pAi;
            Ai[c] = cAr * pAi + cAi * pAr;
            br[c] = cAr * pbr - cAi * pbi + cbr;
            bi[c] = cAr * pbi + cAi * pbr + cbi;
        }
        __syncthreads();
    }
    cr[c * PP + p] = (c == 0) ? 0.f : br[c-1];
    ci[c * PP + p] = (c == 0) ? 0.f : bi[c-1];
}

// ---------------------------------------------------------------------------
// Scan pass 3: replay with carry; overwrite Bu with xs in-place.
// Interleaved layout: one u32 = (re,im) bf16 pair per p -> coalesced.
// 8x-batched loads so HBM/L3 latency overlaps the serial complex chain.
// ---------------------------------------------------------------------------
__global__ void k_scan3(unsigned* __restrict__ bu,
                        const float* __restrict__ lbre, const float* __restrict__ lbim,
                        const float* __restrict__ cr, const float* __restrict__ ci) {
    int p = blockIdx.x * 256 + threadIdx.x;
    int c = blockIdx.y;
    float ar = lbre[p], ai = lbim[p];
    float xr = cr[c * PP + p], xi = ci[c * PP + p];
    unsigned* b = bu + (size_t)c * CHUNK * PP + p;
    for (int j = 0; j < CHUNK; j += 8) {
        unsigned vv[8];
        #pragma unroll
        for (int q = 0; q < 8; q++) vv[q] = b[q * PP];
        unsigned w[8];
        #pragma unroll
        for (int q = 0; q < 8; q++) {
            float br = bf2f((u16)(vv[q] & 0xffff));
            float bi = bf2f((u16)(vv[q] >> 16));
            float nr = ar * xr - ai * xi + br;
            float ni = ar * xi + ai * xr + bi;
            xr = nr; xi = ni;
            w[q] = (unsigned)f2bf(xr) | ((unsigned)f2bf(xi) << 16);
        }
        #pragma unroll
        for (int q = 0; q < 8; q++) b[q * PP] = w[q];
        b += 8 * PP;
    }
}

extern "C" void kernel_launch(void* const* d_in, const int* in_sizes, int n_in,
                              void* d_out, int out_size, void* d_ws, size_t ws_size,
                              hipStream_t stream) {
    const float* u       = (const float*)d_in[0];   // (L,H)
    const float* lre     = (const float*)d_in[1];   // (P,)
    const float* lim     = (const float*)d_in[2];   // (P,)
    const float* B       = (const float*)d_in[3];   // (P,H,2)
    const float* C       = (const float*)d_in[4];   // (H,P,2)
    const float* D       = (const float*)d_in[5];   // (H,)
    const float* logstep = (const float*)d_in[6];   // (P,)
    float* out = (float*)d_out;

    float* w = (float*)d_ws;
    float* lbre = w + 1024;
    float* lbim = w + 1536;
    float* ltre = w + 2048;
    float* ltim = w + 2560;
    float* fr   = w + 4096;                       // NCHUNK*PP each
    float* fi   = fr + NCHUNK * PP;
    float* cr   = fi + NCHUNK * PP;
    float* ci   = cr + NCHUNK * PP;
    u16*   bub  = (u16*)(w + (1 << 20));          // L*2P bf16 = 32 MB (Bu -> xs in-place)
    u16*   ub   = bub + (size_t)LL * NP2;         // L*H bf16 = 32 MB
    u16*   bb   = ub + (size_t)LL * HH;           // 2P*H bf16 = 2 MB
    u16*   cp   = bb + (size_t)NP2 * HH;          // H*2P bf16 = 2 MB

    static int attr_done = 0;
    if (!attr_done) {
        hipFuncSetAttribute(reinterpret_cast<const void*>(k_gemm2<0>),
                            hipFuncAttributeMaxDynamicSharedMemorySize, 131072);
        hipFuncSetAttribute(reinterpret_cast<const void*>(k_gemm2<1>),
                            hipFuncAttributeMaxDynamicSharedMemorySize, 131072);
        attr_done = 1;
    }

    k_prep<<<20482, 256, 0, stream>>>(B, C, u, lre, lim, logstep,
                                      bb, cp, ub, lbre, lbim, ltre, ltim);
    k_gemm2<0><<<(NP2 / BN2) * (LL / BM2), 512, 131072, stream>>>(
        ub, bb, bub, HH, nullptr, nullptr, lbre, lbim, fr, fi);
    k_scan2<<<PP, NCHUNK, 0, stream>>>(fr, fi, ltre, ltim, cr, ci);
    k_scan3<<<dim3(PP / 256, NCHUNK), 256, 0, stream>>>(
        (unsigned*)bub, lbre, lbim, cr, ci);
    k_gemm2<1><<<(HH / BN2) * (LL / BM2), 512, 131072, stream>>>(
        bub, cp, out, NP2, ub, D, nullptr, nullptr, nullptr, nullptr);
}